// Round 1
// baseline (1529.981 us; speedup 1.0000x reference)
//
#include <hip/hip_runtime.h>

#define N_DIM 128   // NODE_DIM
#define L_DIM 64    // EDGE_LBL_DIM
#define F_DIM 128   // EDGE_FT_OUT_DIM

// ---- float <-> order-preserving unsigned (for atomicMax on floats) ----
__device__ __forceinline__ unsigned f2ord(float f) {
    unsigned u = __float_as_uint(f);
    return (u & 0x80000000u) ? ~u : (u | 0x80000000u);
}
__device__ __forceinline__ float ord2f(unsigned u) {
    return (u & 0x80000000u) ? __uint_as_float(u & 0x7fffffffu)
                             : __uint_as_float(~u);
}

// v[k] = sum_f W_fc[k][f] * W_attn[f]   (64 threads, one block)
__global__ void k_prep(const float* __restrict__ Wfc,
                       const float* __restrict__ Wattn,
                       float* __restrict__ v) {
    int k = threadIdx.x;  // 0..63
    float acc = 0.f;
#pragma unroll 8
    for (int f = 0; f < F_DIM; ++f) acc += Wfc[k * F_DIM + f] * Wattn[f];
    v[k] = acc;
}

// One wave (64 lanes) per edge: e = leaky_relu(el.v + h[src].wA2); atomicMax per node
__global__ void k_logits(const float* __restrict__ el,
                         const float* __restrict__ h,
                         const float* __restrict__ Wattn,
                         const float* __restrict__ v,
                         const int* __restrict__ src,
                         float* __restrict__ e_out,
                         unsigned* __restrict__ m_ord,
                         int E) {
    int wave = (int)((blockIdx.x * (unsigned)blockDim.x + threadIdx.x) >> 6);
    int lane = threadIdx.x & 63;
    if (wave >= E) return;
    int sv = src[wave];

    const float* hr = h + (long)sv * N_DIM;
    float s = el[(long)wave * L_DIM + lane] * v[lane];
    s += hr[lane]      * Wattn[F_DIM + lane];
    s += hr[64 + lane] * Wattn[F_DIM + 64 + lane];

    // full-wave (64-lane) butterfly reduce
#pragma unroll
    for (int off = 32; off > 0; off >>= 1) s += __shfl_xor(s, off, 64);

    if (lane == 0) {
        float ev = s > 0.f ? s : 0.01f * s;  // leaky_relu, slope 0.01
        e_out[wave] = ev;
        atomicMax(m_ord + sv, f2ord(ev));
    }
}

// ex = exp(e - m[src]); den[src] += ex   (in-place e -> ex is safe)
__global__ void k_exp(const float* __restrict__ e_in,
                      const int* __restrict__ src,
                      const unsigned* __restrict__ m_ord,
                      float* __restrict__ ex_out,
                      float* __restrict__ den,
                      int E) {
    int i = (int)(blockIdx.x * (unsigned)blockDim.x + threadIdx.x);
    if (i >= E) return;
    int sv = src[i];
    float ex = __expf(e_in[i] - ord2f(m_ord[sv]));
    ex_out[i] = ex;
    atomicAdd(den + sv, ex);
}

// out[e][f] = (ex[e]/den[src[e]]) * (el[e] . Wfc[:,f])
// Thread owns feature f; Wfc column lives in 64 registers; 2 edges per block-iter.
__global__ void __launch_bounds__(256) k_out(const float* __restrict__ el,
                                             const float* __restrict__ Wfc,
                                             const int* __restrict__ src,
                                             const float* __restrict__ ex,
                                             const float* __restrict__ den,
                                             float* __restrict__ out,
                                             int E) {
    int f = threadIdx.x & (F_DIM - 1);
    int sub = threadIdx.x >> 7;  // 0 or 1 (edge within pair)

    // Load Wfc column f into registers (coalesced across threads; once per block)
    float w[L_DIM];
#pragma unroll
    for (int k = 0; k < L_DIM; ++k) w[k] = Wfc[k * F_DIM + f];

    for (long base = (long)blockIdx.x * 2; base < E; base += (long)gridDim.x * 2) {
        long e = base + sub;
        if (e >= E) continue;
        const float4* elv = (const float4*)(el + e * L_DIM);
        float acc = 0.f;
#pragma unroll
        for (int k4 = 0; k4 < L_DIM / 4; ++k4) {
            float4 q = elv[k4];  // broadcast load (same addr across the wave)
            acc += q.x * w[4 * k4 + 0];
            acc += q.y * w[4 * k4 + 1];
            acc += q.z * w[4 * k4 + 2];
            acc += q.w * w[4 * k4 + 3];
        }
        float gamma = ex[e] / den[src[e]];
        out[e * F_DIM + f] = gamma * acc;
    }
}

extern "C" void kernel_launch(void* const* d_in, const int* in_sizes, int n_in,
                              void* d_out, int out_size, void* d_ws, size_t ws_size,
                              hipStream_t stream) {
    const float* h     = (const float*)d_in[0];
    const float* el    = (const float*)d_in[1];
    const float* Wfc   = (const float*)d_in[2];
    const float* Wattn = (const float*)d_in[3];
    const int*   src   = (const int*)d_in[4];
    float* out = (float*)d_out;

    int N = in_sizes[0] / N_DIM;   // 50000
    int E = in_sizes[4];           // 800000

    // workspace layout (floats): [v:64][m_ord:N][den:N][e/ex:E]
    float*    v_ws  = (float*)d_ws;
    unsigned* m_ord = (unsigned*)d_ws + 64;
    float*    den   = (float*)d_ws + 64 + N;
    float*    e_buf = (float*)d_ws + 64 + 2 * (size_t)N;

    // zero-init m_ord (ordered-uint 0 == -inf) and den (0.0f) in one memset
    hipMemsetAsync(m_ord, 0, (size_t)2 * N * sizeof(float), stream);

    k_prep<<<1, 64, 0, stream>>>(Wfc, Wattn, v_ws);
    k_logits<<<(E + 3) / 4, 256, 0, stream>>>(el, h, Wattn, v_ws, src, e_buf, m_ord, E);
    k_exp<<<(E + 255) / 256, 256, 0, stream>>>(e_buf, src, m_ord, e_buf, den, E);
    k_out<<<2048, 256, 0, stream>>>(el, Wfc, src, e_buf, den, out, E);
}